// Round 1
// baseline (1533.640 us; speedup 1.0000x reference)
//
#include <hip/hip_runtime.h>
#include <math.h>

#define NT   96      // in_steps == out_steps
#define NC   64      // d_model
#define DIN  128     // d_inner
#define NS   16      // d_state
#define NV   358     // nodes
#define NN   8       // batch
#define NTH  512
#define CLIPV 10000.0f

typedef float f4 __attribute__((ext_vector_type(4)));

__device__ __forceinline__ float hsum(f4 a) { return (a.x + a.y) + (a.z + a.w); }
__device__ __forceinline__ float siluf(float a) { return a / (1.f + __expf(-a)); }
__device__ __forceinline__ float softplusf(float a) {
    return (a > 20.f) ? a : log1pf(__expf(a));
}
__device__ __forceinline__ float safef(float a) {
    if (__builtin_isnan(a)) return 0.f;
    return fminf(fmaxf(a, -CLIPV), CLIPV);
}

extern "C" __global__ void __launch_bounds__(NTH, 4)
mamba_temporal(const float* __restrict__ x,     // (8,96,64,358)
               const float* __restrict__ Win,   // (256,64)
               const float* __restrict__ Wc,    // (128,4)
               const float* __restrict__ bc,    // (128)
               const float* __restrict__ Wx,    // (36,128)
               const float* __restrict__ Wdt,   // (128,4)
               const float* __restrict__ bdt,   // (128)
               const float* __restrict__ Alog,  // (128,16)
               const float* __restrict__ Dp,    // (128)
               const float* __restrict__ Wout,  // (64,128)
               const float* __restrict__ Wt,    // (96,96)
               const float* __restrict__ bt,    // (96)
               float* __restrict__ out)         // (8,96,64,358)
{
    extern __shared__ float lds[];
    float* sB = lds;            // [NT][DIN] : xin -> xc -> y
    float* sR = lds + NT*DIN;   // [NT][NC] (x, later h1) / [NT][36] (dt,B,C)

    const int tid = threadIdx.x;
    const int bid = blockIdx.x;
    const int n   = bid & 7;     // XCD-friendly: same n -> same XCD (round robin %8)
    const int v   = bid >> 3;    // consecutive v share HBM cache lines within an XCD

    // ---------- phase 1: stage x[n,:,:,v] -> sR[NT][NC]
    for (int i = tid; i < NT*NC; i += NTH) {
        int l = i >> 6, c = i & 63;
        sR[i] = x[((size_t)((n*NT + l)*NC + c))*NV + v];
    }
    __syncthreads();

    // ---------- phase 2: xin = x @ Win[0:128,:]^T -> sB
    {
        const int e  = tid & 127;
        const int l0 = tid >> 7;          // 0..3
        const float* wr = Win + e*NC;
        f4 w[16];
        #pragma unroll
        for (int k = 0; k < 16; ++k) w[k] = *(const f4*)(wr + 4*k);
        for (int j = 0; j < 24; ++j) {
            int l = l0 + 4*j;
            f4 acc = {0.f, 0.f, 0.f, 0.f};
            #pragma unroll
            for (int k = 0; k < 16; ++k)
                acc += w[k] * *(const f4*)(sR + l*NC + 4*k);
            sB[l*DIN + e] = hsum(acc);
        }
    }
    __syncthreads();

    // ---------- phase 3: causal depthwise conv (K=4) + SiLU, in place on sB
    {
        const int d  = tid & 127;
        const int l0 = tid >> 7;
        f4 cw = *(const f4*)(Wc + 4*d);
        float cb0 = bc[d];
        float val[24];
        #pragma unroll
        for (int j = 0; j < 24; ++j) {
            int l = l0 + 4*j;
            float a = cb0 + sB[l*DIN + d] * cw.w;
            if (l >= 1) a += sB[(l-1)*DIN + d] * cw.z;
            if (l >= 2) a += sB[(l-2)*DIN + d] * cw.y;
            if (l >= 3) a += sB[(l-3)*DIN + d] * cw.x;
            val[j] = siluf(a);
        }
        __syncthreads();
        #pragma unroll
        for (int j = 0; j < 24; ++j) {
            int l = l0 + 4*j;
            sB[l*DIN + d] = val[j];
        }
    }
    __syncthreads();

    // ---------- phase 4: dbl = xc @ Wx^T -> sR[NT][36] (dt_low | B | C)
    for (int i = tid; i < NT*36; i += NTH) {
        int l = i / 36, jj = i - l*36;
        const float* wr = Wx + jj*DIN;
        const float* xr = sB + l*DIN;
        f4 acc = {0.f, 0.f, 0.f, 0.f};
        #pragma unroll
        for (int k = 0; k < 32; ++k)
            acc += *(const f4*)(wr + 4*k) * *(const f4*)(xr + 4*k);
        sR[i] = hsum(acc);
    }
    __syncthreads();

    // ---------- phase 5/6: selective scan; dt_proj+softplus fused per step.
    // thread-quad (sq=0..3) per channel d; 4 states per lane; y overwrites xc slot.
    {
        const int d  = tid >> 2;
        const int sq = tid & 3;
        f4 A4;
        A4.x = -__expf(Alog[d*NS + 4*sq + 0]);
        A4.y = -__expf(Alog[d*NS + 4*sq + 1]);
        A4.z = -__expf(Alog[d*NS + 4*sq + 2]);
        A4.w = -__expf(Alog[d*NS + 4*sq + 3]);
        f4 wdt = *(const f4*)(Wdt + 4*d);
        const float bdt0 = bdt[d];
        const float Dd   = Dp[d];
        f4 h = {0.f, 0.f, 0.f, 0.f};
        for (int l = 0; l < NT; ++l) {
            const float* rb = sR + l*36;
            f4 dl = *(const f4*)rb;                       // dt_low (broadcast)
            float dtr = dl.x*wdt.x + dl.y*wdt.y + dl.z*wdt.z + dl.w*wdt.w + bdt0;
            float dt  = softplusf(dtr);
            float xv  = sB[l*DIN + d];
            float u   = dt * xv;
            f4 B4 = *(const f4*)(rb + 4  + 4*sq);
            f4 C4 = *(const f4*)(rb + 20 + 4*sq);
            h.x = __expf(dt*A4.x)*h.x + u*B4.x;
            h.y = __expf(dt*A4.y)*h.y + u*B4.y;
            h.z = __expf(dt*A4.z)*h.z + u*B4.z;
            h.w = __expf(dt*A4.w)*h.w + u*B4.w;
            float y = h.x*C4.x + h.y*C4.y + h.z*C4.z + h.w*C4.w;
            y += __shfl_xor(y, 1);
            y += __shfl_xor(y, 2);
            if (sq == 0) sB[l*DIN + d] = y + xv*Dd;       // only this quad touches slot
        }
    }
    __syncthreads();

    // ---------- phase 7a: re-stage x (sR was overwritten by dt/B/C)
    for (int i = tid; i < NT*NC; i += NTH) {
        int l = i >> 6, c = i & 63;
        sR[i] = x[((size_t)((n*NT + l)*NC + c))*NV + v];
    }
    __syncthreads();

    // ---------- phase 7: y *= silu(z), z = x @ Win[128:256,:]^T
    {
        const int d  = tid & 127;
        const int l0 = tid >> 7;
        const float* wr = Win + (DIN + d)*NC;
        f4 w[16];
        #pragma unroll
        for (int k = 0; k < 16; ++k) w[k] = *(const f4*)(wr + 4*k);
        for (int j = 0; j < 24; ++j) {
            int l = l0 + 4*j;
            f4 acc = {0.f, 0.f, 0.f, 0.f};
            #pragma unroll
            for (int k = 0; k < 16; ++k)
                acc += w[k] * *(const f4*)(sR + l*NC + 4*k);
            float z = hsum(acc);
            sB[l*DIN + d] *= siluf(z);
        }
    }
    __syncthreads();

    // ---------- phase 8: h1 = y @ Wout^T, _safe -> sR[NT][NC]
    {
        const int e1 = tid & 63;
        const int l0 = tid >> 6;          // 0..7
        const float* wr = Wout + e1*DIN;
        for (int j = 0; j < 12; ++j) {
            int l = l0 + 8*j;
            const float* yr = sB + l*DIN;
            f4 acc = {0.f, 0.f, 0.f, 0.f};
            #pragma unroll
            for (int k = 0; k < 32; ++k)
                acc += *(const f4*)(wr + 4*k) * *(const f4*)(yr + 4*k);
            sR[l*NC + e1] = safef(hsum(acc));
        }
    }
    __syncthreads();

    // ---------- phase 9: time_proj + bias, _safe, scatter-store
    for (int i = tid; i < NT*16; i += NTH) {   // (o, quad-of-c)
        int o = i >> 4, q = i & 15;
        const float* wr = Wt + o*NT;
        float bo = bt[o];
        f4 acc = {bo, bo, bo, bo};
        #pragma unroll 4
        for (int t = 0; t < NT; ++t)
            acc += wr[t] * *(const f4*)(sR + t*NC + 4*q);
        size_t base = ((size_t)((n*NT + o)*NC + 4*q))*NV + v;
        out[base]        = safef(acc.x);
        out[base +   NV] = safef(acc.y);
        out[base + 2*NV] = safef(acc.z);
        out[base + 3*NV] = safef(acc.w);
    }
}

extern "C" void kernel_launch(void* const* d_in, const int* in_sizes, int n_in,
                              void* d_out, int out_size, void* d_ws, size_t ws_size,
                              hipStream_t stream) {
    const size_t shmem = (size_t)(NT*DIN + NT*NC) * sizeof(float);  // 73728 B
    // opt-in for >64KB dynamic LDS (gfx950 allows up to 160KB); idempotent host call
    (void)hipFuncSetAttribute((const void*)mamba_temporal,
                              hipFuncAttributeMaxDynamicSharedMemorySize,
                              (int)shmem);
    mamba_temporal<<<dim3(NN*NV), dim3(NTH), shmem, stream>>>(
        (const float*)d_in[0],  (const float*)d_in[1],  (const float*)d_in[2],
        (const float*)d_in[3],  (const float*)d_in[4],  (const float*)d_in[5],
        (const float*)d_in[6],  (const float*)d_in[7],  (const float*)d_in[8],
        (const float*)d_in[9],  (const float*)d_in[10], (const float*)d_in[11],
        (float*)d_out);
}

// Round 2
// 517.183 us; speedup vs baseline: 2.9654x; 2.9654x over previous
//
#include <hip/hip_runtime.h>
#include <math.h>

#define NT   96      // in_steps == out_steps
#define NC   64      // d_model
#define DIN  128     // d_inner
#define NS   16      // d_state
#define NV   358     // nodes
#define NN   8       // batch
#define NTH  512
#define CLIPV 10000.0f

typedef float f4 __attribute__((ext_vector_type(4)));
typedef __attribute__((ext_vector_type(8))) short bf8;   // 8 bf16 in 4 VGPRs

// ---- LDS layout (u16 units) ----
// XC buffer [96][128] bf16: hi at 0, lo at 12288        (bytes 0..49152)
// R1 region (u16 base 24576):
//   x   [96][64] bf16: hi at 24576, lo at 30720         (dead after P2)
//   dbl [96][36] f32 at float-offset 12288              (P4 -> scan)
//   h1T [64][104] bf16: hi at 24576, lo at 31232        (P8 -> P9)
#define XCH 0
#define XCL 12288
#define XH  24576
#define XL  30720
#define DBLF 12288        // float units
#define H1H 24576
#define H1L 31232
#define LDS_BYTES 75776   // 37888 u16

__device__ __forceinline__ float siluf(float a) { return a / (1.f + __expf(-a)); }
__device__ __forceinline__ float safef(float a) {
    if (__builtin_isnan(a)) return 0.f;
    return fminf(fmaxf(a, -CLIPV), CLIPV);
}
__device__ __forceinline__ float bf2f(unsigned short h) {
    return __uint_as_float(((unsigned)h) << 16);
}
__device__ __forceinline__ void splitf(float v, unsigned short& h, unsigned short& l) {
    unsigned u = __float_as_uint(v);
    h = (unsigned short)(u >> 16);
    float r = v - __uint_as_float(u & 0xffff0000u);
    l = (unsigned short)(__float_as_uint(r) >> 16);
}
// swizzled u16 indices (16B-block XOR to spread rows across banks)
__device__ __forceinline__ int xcIdx(int l, int d) { return l*128 + (d ^ ((l & 15) << 3)); }
__device__ __forceinline__ int xIdx (int l, int c) { return l*64  + (c ^ ((l & 7)  << 3)); }

__device__ __forceinline__ f4 MFMA(bf8 a, bf8 b, f4 c) {
    return __builtin_amdgcn_mfma_f32_16x16x32_bf16(a, b, c, 0, 0, 0);
}
// load 8 consecutive fp32, split into bf16 hi/lo fragments
__device__ __forceinline__ void pack8(const float* p, bf8& h, bf8& l) {
    f4 a = *(const f4*)p, b = *(const f4*)(p + 4);
    float vv[8] = {a.x, a.y, a.z, a.w, b.x, b.y, b.z, b.w};
    #pragma unroll
    for (int j = 0; j < 8; ++j) {
        unsigned u = __float_as_uint(vv[j]);
        h[j] = (short)(u >> 16);
        float r = vv[j] - __uint_as_float(u & 0xffff0000u);
        l[j] = (short)(__float_as_uint(r) >> 16);
    }
}

extern "C" __global__ void __launch_bounds__(NTH, 4)
mamba_mfma(const float* __restrict__ x,     // (8,96,64,358)
           const float* __restrict__ Win,   // (256,64)
           const float* __restrict__ Wc,    // (128,4)
           const float* __restrict__ bc,    // (128)
           const float* __restrict__ Wx,    // (36,128)
           const float* __restrict__ Wdt,   // (128,4)
           const float* __restrict__ bdt,   // (128)
           const float* __restrict__ Alog,  // (128,16)
           const float* __restrict__ Dp,    // (128)
           const float* __restrict__ Wout,  // (64,128)
           const float* __restrict__ Wt,    // (96,96)
           const float* __restrict__ bt,    // (96)
           float* __restrict__ out)         // (8,96,64,358)
{
    extern __shared__ unsigned short u16[];
    float* f32 = (float*)u16;

    const int tid  = threadIdx.x;
    const int bid  = blockIdx.x;
    const int n    = bid & 7;       // XCD round-robin friendly
    const int v    = bid >> 3;
    const int lane = tid & 63;
    const int w    = tid >> 6;      // wave id 0..7
    const int r16  = lane & 15;
    const int kg   = lane >> 4;     // k-group 0..3

    // ---------- P0: stage x -> bf16 hi/lo in R1
    for (int i = tid; i < NT*NC; i += NTH) {
        int l = i >> 6, c = i & 63;
        float xv = x[((size_t)((n*NT + l)*NC + c))*NV + v];
        unsigned short h, lo; splitf(xv, h, lo);
        int id = xIdx(l, c);
        u16[XH + id] = h; u16[XL + id] = lo;
    }
    __syncthreads();

    // ---------- P2: xz = x @ Win^T via MFMA bf16x3. xin -> XC LDS, z -> regs
    f4 zr[6];
    {
        bf8 bxh[2], bxl[2], bzh[2], bzl[2];
        const int exi = 16*w + r16;          // xin column (0..127)
        #pragma unroll
        for (int ks = 0; ks < 2; ++ks) {
            pack8(Win + exi*NC        + 32*ks + 8*kg, bxh[ks], bxl[ks]);
            pack8(Win + (DIN+exi)*NC  + 32*ks + 8*kg, bzh[ks], bzl[ks]);
        }
        #pragma unroll
        for (int mt = 0; mt < 6; ++mt) {
            f4 ax = {0.f,0.f,0.f,0.f}, az = {0.f,0.f,0.f,0.f};
            #pragma unroll
            for (int ks = 0; ks < 2; ++ks) {
                int l  = 16*mt + r16;
                int id = xIdx(l, 8*kg + 32*ks);
                bf8 ah = *(const bf8*)(u16 + XH + id);
                bf8 al = *(const bf8*)(u16 + XL + id);
                ax = MFMA(ah, bxh[ks], ax); ax = MFMA(ah, bxl[ks], ax); ax = MFMA(al, bxh[ks], ax);
                az = MFMA(ah, bzh[ks], az); az = MFMA(ah, bzl[ks], az); az = MFMA(al, bzh[ks], az);
            }
            zr[mt] = az;
            #pragma unroll
            for (int i = 0; i < 4; ++i) {
                int row = 4*kg + i + 16*mt, col = r16 + 16*w;
                unsigned short h, lo; splitf(ax[i], h, lo);
                int id = xcIdx(row, col);
                u16[XCH + id] = h; u16[XCL + id] = lo;
            }
        }
    }
    __syncthreads();

    // ---------- P3: causal depthwise conv (K=4) + SiLU, in place on XC
    {
        const int d  = tid & 127;
        const int l0 = tid >> 7;
        f4 cw = *(const f4*)(Wc + 4*d);
        const float cb0 = bc[d];
        float val[24];
        #pragma unroll
        for (int j = 0; j < 24; ++j) {
            int l = l0 + 4*j;
            int i0 = xcIdx(l, d);
            float a = cb0 + (bf2f(u16[XCH+i0]) + bf2f(u16[XCL+i0])) * cw.w;
            if (l >= 1) { int i1 = xcIdx(l-1, d); a += (bf2f(u16[XCH+i1]) + bf2f(u16[XCL+i1])) * cw.z; }
            if (l >= 2) { int i2 = xcIdx(l-2, d); a += (bf2f(u16[XCH+i2]) + bf2f(u16[XCL+i2])) * cw.y; }
            if (l >= 3) { int i3 = xcIdx(l-3, d); a += (bf2f(u16[XCH+i3]) + bf2f(u16[XCL+i3])) * cw.x; }
            val[j] = siluf(a);
        }
        __syncthreads();
        #pragma unroll
        for (int j = 0; j < 24; ++j) {
            int l = l0 + 4*j;
            unsigned short h, lo; splitf(val[j], h, lo);
            int id = xcIdx(l, d);
            u16[XCH + id] = h; u16[XCL + id] = lo;
        }
    }
    __syncthreads();

    // ---------- P4: dbl = xc @ Wx^T (96x36) via MFMA -> dbl f32
    for (int tt = w; tt < 18; tt += 8) {
        int mt = tt / 3, nt = tt - 3*(tt/3);
        int nn = 16*nt + r16;                 // Wx row (valid < 36)
        bool okn = nn < 36;
        f4 acc = {0.f,0.f,0.f,0.f};
        #pragma unroll
        for (int ks = 0; ks < 4; ++ks) {
            bf8 bh = (bf8)(short)0, bl = (bf8)(short)0;
            if (okn) pack8(Wx + nn*DIN + 32*ks + 8*kg, bh, bl);
            int l  = 16*mt + r16;
            int id = xcIdx(l, 8*kg + 32*ks);
            bf8 ah = *(const bf8*)(u16 + XCH + id);
            bf8 al = *(const bf8*)(u16 + XCL + id);
            acc = MFMA(ah, bh, acc); acc = MFMA(ah, bl, acc); acc = MFMA(al, bh, acc);
        }
        #pragma unroll
        for (int i = 0; i < 4; ++i) {
            int row = 4*kg + i + 16*mt, col = r16 + 16*nt;
            if (col < 36) f32[DBLF + row*36 + col] = acc[i];
        }
    }
    __syncthreads();

    // ---------- P5: selective scan (quad of lanes per channel, 4 states each)
    {
        const int d  = tid >> 2;
        const int sq = tid & 3;
        f4 A4;
        A4.x = -__expf(Alog[d*NS + 4*sq + 0]);
        A4.y = -__expf(Alog[d*NS + 4*sq + 1]);
        A4.z = -__expf(Alog[d*NS + 4*sq + 2]);
        A4.w = -__expf(Alog[d*NS + 4*sq + 3]);
        f4 wdt = *(const f4*)(Wdt + 4*d);
        const float bdt0 = bdt[d];
        const float Dd   = Dp[d];
        const float* db  = f32 + DBLF;
        f4 h = {0.f,0.f,0.f,0.f};
        for (int l = 0; l < NT; ++l) {
            const float* rb = db + l*36;
            f4 dl = *(const f4*)rb;
            float dtr = dl.x*wdt.x + dl.y*wdt.y + dl.z*wdt.z + dl.w*wdt.w + bdt0;
            float dt  = (dtr > 20.f) ? dtr : __logf(1.f + __expf(dtr));
            int  idx  = xcIdx(l, d);
            float xv  = bf2f(u16[XCH+idx]) + bf2f(u16[XCL+idx]);
            float u   = dt * xv;
            f4 B4 = *(const f4*)(rb + 4  + 4*sq);
            f4 C4 = *(const f4*)(rb + 20 + 4*sq);
            h.x = __expf(dt*A4.x)*h.x + u*B4.x;
            h.y = __expf(dt*A4.y)*h.y + u*B4.y;
            h.z = __expf(dt*A4.z)*h.z + u*B4.z;
            h.w = __expf(dt*A4.w)*h.w + u*B4.w;
            float y = h.x*C4.x + h.y*C4.y + h.z*C4.z + h.w*C4.w;
            y += __shfl_xor(y, 1);
            y += __shfl_xor(y, 2);
            if (sq == 0) {
                unsigned short hh, ll; splitf(y + xv*Dd, hh, ll);
                u16[XCH+idx] = hh; u16[XCL+idx] = ll;
            }
        }
    }
    __syncthreads();

    // ---------- P5b: y *= silu(z) (z frags live in zr with P2 D-layout)
    #pragma unroll
    for (int mt = 0; mt < 6; ++mt) {
        #pragma unroll
        for (int i = 0; i < 4; ++i) {
            int row = 4*kg + i + 16*mt, col = r16 + 16*w;
            int id = xcIdx(row, col);
            float y = bf2f(u16[XCH+id]) + bf2f(u16[XCL+id]);
            y *= siluf(zr[mt][i]);
            unsigned short hh, ll; splitf(y, hh, ll);
            u16[XCH+id] = hh; u16[XCL+id] = ll;
        }
    }
    __syncthreads();

    // ---------- P8: h1 = safe(y @ Wout^T) -> h1T (transposed, bf16 hi/lo)
    for (int tt = w; tt < 24; tt += 8) {
        int mt = tt >> 2, nt = tt & 3;
        int nn = 16*nt + r16;                 // Wout row (0..63)
        f4 acc = {0.f,0.f,0.f,0.f};
        #pragma unroll
        for (int ks = 0; ks < 4; ++ks) {
            bf8 bh, bl; pack8(Wout + nn*DIN + 32*ks + 8*kg, bh, bl);
            int l  = 16*mt + r16;
            int id = xcIdx(l, 8*kg + 32*ks);
            bf8 ah = *(const bf8*)(u16 + XCH + id);
            bf8 al = *(const bf8*)(u16 + XCL + id);
            acc = MFMA(ah, bh, acc); acc = MFMA(ah, bl, acc); acc = MFMA(al, bh, acc);
        }
        #pragma unroll
        for (int i = 0; i < 4; ++i) {
            int t = 4*kg + i + 16*mt, c = r16 + 16*nt;
            unsigned short hh, ll; splitf(safef(acc[i]), hh, ll);
            int id = c*104 + t;
            u16[H1H + id] = hh; u16[H1L + id] = ll;
        }
    }
    __syncthreads();

    // ---------- P9: out[o][c] = safe( sum_t Wt[o][t]*h1[t][c] + bt[o] )
    for (int tt = w; tt < 24; tt += 8) {
        int mt = tt >> 2, nt = tt & 3;
        int oo = 16*mt + r16;                 // Wt row (o)
        f4 acc = {0.f,0.f,0.f,0.f};
        #pragma unroll
        for (int ks = 0; ks < 3; ++ks) {
            bf8 ah, al; pack8(Wt + oo*NT + 32*ks + 8*kg, ah, al);
            int c  = r16 + 16*nt;
            int id = c*104 + 8*kg + 32*ks;
            bf8 bh = *(const bf8*)(u16 + H1H + id);
            bf8 bl = *(const bf8*)(u16 + H1L + id);
            acc = MFMA(ah, bh, acc); acc = MFMA(ah, bl, acc); acc = MFMA(al, bh, acc);
        }
        #pragma unroll
        for (int i = 0; i < 4; ++i) {
            int o = 4*kg + i + 16*mt, c = r16 + 16*nt;
            float valo = safef(acc[i] + bt[o]);
            out[((size_t)((n*NT + o)*NC + c))*NV + v] = valo;
        }
    }
}

extern "C" void kernel_launch(void* const* d_in, const int* in_sizes, int n_in,
                              void* d_out, int out_size, void* d_ws, size_t ws_size,
                              hipStream_t stream) {
    (void)hipFuncSetAttribute((const void*)mamba_mfma,
                              hipFuncAttributeMaxDynamicSharedMemorySize,
                              LDS_BYTES);
    mamba_mfma<<<dim3(NN*NV), dim3(NTH), LDS_BYTES, stream>>>(
        (const float*)d_in[0],  (const float*)d_in[1],  (const float*)d_in[2],
        (const float*)d_in[3],  (const float*)d_in[4],  (const float*)d_in[5],
        (const float*)d_in[6],  (const float*)d_in[7],  (const float*)d_in[8],
        (const float*)d_in[9],  (const float*)d_in[10], (const float*)d_in[11],
        (float*)d_out);
}

// Round 3
// 468.252 us; speedup vs baseline: 3.2752x; 1.1045x over previous
//
#include <hip/hip_runtime.h>
#include <math.h>

#define NT   96
#define NC   64
#define DIN  128
#define NS   16
#define NV   358
#define NN   8
#define NTH  512
#define CLIPV 10000.0f

typedef float f4 __attribute__((ext_vector_type(4)));
typedef unsigned u4v __attribute__((ext_vector_type(4)));
typedef __attribute__((ext_vector_type(8))) short bf8;

// ---- LDS map ----
// u32[0..12288)     : XIN_T (xin transposed [d][96], packed hi|lo) -> then XC [96][128] packed u32
// u16[24576..30720) : XH (x hi)  [dead after P2]
// u16[30720..36864) : XL (x lo)  [dead after P2]
// f32[12288..12672) : dtl [96][4]          (P4 -> P4b)
// u16[25344..28416) : BCH [96][32] bf16-hi (P4 -> scan)  (B0..3|C0..3 per sq, 16B records)
// u16[24576..31232) : H1H [64][104]        (P8 -> P9)
// u16[31232..37888) : H1L
#define XH   24576
#define XL   30720
#define DTLF 12288
#define BCHU 25344
#define H1H  24576
#define H1L  31232
#define LDS_BYTES 75776

__device__ __forceinline__ float siluf(float a) { return a / (1.f + __expf(-a)); }
__device__ __forceinline__ float safef(float a) {
    if (__builtin_isnan(a)) return 0.f;
    return fminf(fmaxf(a, -CLIPV), CLIPV);
}
__device__ __forceinline__ void splitf(float v, unsigned short& h, unsigned short& l) {
    unsigned u = __float_as_uint(v);
    h = (unsigned short)(u >> 16);
    float r = v - __uint_as_float(u & 0xffff0000u);
    l = (unsigned short)(__float_as_uint(r) >> 16);
}
__device__ __forceinline__ unsigned packu(float v) {         // (hi16|lo16) packed
    unsigned uu = __float_as_uint(v);
    unsigned hb = uu & 0xffff0000u;
    float r = v - __uint_as_float(hb);
    return hb | (__float_as_uint(r) >> 16);
}
__device__ __forceinline__ float unpk(unsigned p) {
    return __uint_as_float(p & 0xffff0000u) + __uint_as_float(p << 16);
}
// swizzled indices
__device__ __forceinline__ int xIdx(int l, int c) { return l*64 + (c ^ ((l & 7) << 3)); }      // u16, x stage
__device__ __forceinline__ int xinT(int d, int lb) { return d*96 + 4*(lb ^ (d & 7)); }          // u32, block base
__device__ __forceinline__ int xcw(int l, int c)  { return l*128 + (c ^ ((l & 7) << 2)); }      // u32, XC

template<int CTRL>
__device__ __forceinline__ float dppf(float v) {   // quad_perm DPP move
    return __int_as_float(__builtin_amdgcn_mov_dpp(__float_as_int(v), CTRL, 0xF, 0xF, true));
}

__device__ __forceinline__ f4 MFMA(bf8 a, bf8 b, f4 c) {
    return __builtin_amdgcn_mfma_f32_16x16x32_bf16(a, b, c, 0, 0, 0);
}
__device__ __forceinline__ void pack8(const float* p, bf8& h, bf8& l) {
    f4 a = *(const f4*)p, b = *(const f4*)(p + 4);
    float vv[8] = {a.x, a.y, a.z, a.w, b.x, b.y, b.z, b.w};
    #pragma unroll
    for (int j = 0; j < 8; ++j) {
        unsigned u = __float_as_uint(vv[j]);
        h[j] = (short)(u >> 16);
        float r = vv[j] - __uint_as_float(u & 0xffff0000u);
        l[j] = (short)(__float_as_uint(r) >> 16);
    }
}
// extract hi/lo bf8 fragments (8 consecutive c) from packed-u32 XC
__device__ __forceinline__ void fragFromXC(const unsigned* XC, int l, int c0, bf8& ah, bf8& al) {
    u4v a = *(const u4v*)(XC + xcw(l, c0));
    u4v b = *(const u4v*)(XC + xcw(l, c0 + 4));
    u4v hs, ls;
    hs.x = __builtin_amdgcn_perm(a.y, a.x, 0x07060302); hs.y = __builtin_amdgcn_perm(a.w, a.z, 0x07060302);
    hs.z = __builtin_amdgcn_perm(b.y, b.x, 0x07060302); hs.w = __builtin_amdgcn_perm(b.w, b.z, 0x07060302);
    ls.x = __builtin_amdgcn_perm(a.y, a.x, 0x05040100); ls.y = __builtin_amdgcn_perm(a.w, a.z, 0x05040100);
    ls.z = __builtin_amdgcn_perm(b.y, b.x, 0x05040100); ls.w = __builtin_amdgcn_perm(b.w, b.z, 0x05040100);
    ah = __builtin_bit_cast(bf8, hs);
    al = __builtin_bit_cast(bf8, ls);
}

extern "C" __global__ void __launch_bounds__(NTH, 4)
mamba_mfma(const float* __restrict__ x,     const float* __restrict__ Win,
           const float* __restrict__ Wc,    const float* __restrict__ bc,
           const float* __restrict__ Wx,    const float* __restrict__ Wdt,
           const float* __restrict__ bdt,   const float* __restrict__ Alog,
           const float* __restrict__ Dp,    const float* __restrict__ Wout,
           const float* __restrict__ Wt,    const float* __restrict__ bt,
           float* __restrict__ out)
{
    extern __shared__ unsigned short u16[];
    float*    f32 = (float*)u16;
    unsigned* XCU = (unsigned*)u16;

    const int tid  = threadIdx.x;
    const int bid  = blockIdx.x;
    const int n    = bid & 7;
    const int v    = bid >> 3;
    const int lane = tid & 63;
    const int w    = tid >> 6;
    const int r16  = lane & 15;
    const int kg   = lane >> 4;

    // ---------- P0: stage x -> XH/XL
    for (int i = tid; i < NT*NC; i += NTH) {
        int l = i >> 6, c = i & 63;
        float xv = x[((size_t)((n*NT + l)*NC + c))*NV + v];
        unsigned short h, lo; splitf(xv, h, lo);
        int id = xIdx(l, c);
        u16[XH + id] = h; u16[XL + id] = lo;
    }
    __syncthreads();

    // ---------- P2: xz = x @ Win^T. xin -> XIN_T (packed u32), z -> regs
    f4 zr[6];
    {
        bf8 bxh[2], bxl[2], bzh[2], bzl[2];
        const int exi = 16*w + r16;
        #pragma unroll
        for (int ks = 0; ks < 2; ++ks) {
            pack8(Win + exi*NC       + 32*ks + 8*kg, bxh[ks], bxl[ks]);
            pack8(Win + (DIN+exi)*NC + 32*ks + 8*kg, bzh[ks], bzl[ks]);
        }
        #pragma unroll
        for (int mt = 0; mt < 6; ++mt) {
            f4 ax = {0.f,0.f,0.f,0.f}, az = {0.f,0.f,0.f,0.f};
            #pragma unroll
            for (int ks = 0; ks < 2; ++ks) {
                int id = xIdx(16*mt + r16, 8*kg + 32*ks);
                bf8 ah = *(const bf8*)(u16 + XH + id);
                bf8 al = *(const bf8*)(u16 + XL + id);
                ax = MFMA(ah, bxh[ks], ax); ax = MFMA(ah, bxl[ks], ax); ax = MFMA(al, bxh[ks], ax);
                az = MFMA(ah, bzh[ks], az); az = MFMA(ah, bzl[ks], az); az = MFMA(al, bzh[ks], az);
            }
            zr[mt] = az;
            u4v pk;
            #pragma unroll
            for (int i = 0; i < 4; ++i) pk[i] = packu(ax[i]);   // rows l = 16mt+4kg+i
            *(u4v*)(XCU + xinT(exi, 4*mt + kg)) = pk;
        }
    }
    __syncthreads();

    // ---------- P3: conv. read window from XIN_T, barrier, write xc -> XC (in place)
    {
        const int d  = tid & 127;
        const int ck = tid >> 7;           // l-chunk 0..3 (24 steps each)
        u4v blk[7];
        #pragma unroll
        for (int b = 0; b < 7; ++b) {
            int lb = 6*ck - 1 + b;
            u4v t = {0,0,0,0};
            if (lb >= 0) t = *(const u4v*)(XCU + xinT(d, lb));
            blk[b] = t;
        }
        __syncthreads();
        float xf[28];                       // l = 24*ck - 4 + p
        #pragma unroll
        for (int p = 0; p < 28; ++p) {
            unsigned uu = blk[p>>2][p&3];
            xf[p] = unpk(uu);
        }
        f4 cw = *(const f4*)(Wc + 4*d);
        const float cb = bc[d];
        #pragma unroll
        for (int j = 0; j < 24; ++j) {
            int l = 24*ck + j;
            float a = cb + cw.x*xf[j+1] + cw.y*xf[j+2] + cw.z*xf[j+3] + cw.w*xf[j+4];
            XCU[xcw(l, d)] = packu(siluf(a));
        }
    }
    __syncthreads();

    // ---------- P4: dbl = xc @ Wx^T -> dtl (f32) + BCH (bf16-hi, RNE)
    for (int tt = w; tt < 18; tt += 8) {
        int mt = tt / 3, nt = tt - 3*(tt/3);
        int nn = 16*nt + r16;
        bool okn = nn < 36;
        f4 acc = {0.f,0.f,0.f,0.f};
        #pragma unroll
        for (int ks = 0; ks < 4; ++ks) {
            bf8 bh = (bf8)(short)0, bl = (bf8)(short)0;
            if (okn) pack8(Wx + nn*DIN + 32*ks + 8*kg, bh, bl);
            bf8 ah, al; fragFromXC(XCU, 16*mt + r16, 8*kg + 32*ks, ah, al);
            acc = MFMA(ah, bh, acc); acc = MFMA(ah, bl, acc); acc = MFMA(al, bh, acc);
        }
        #pragma unroll
        for (int i = 0; i < 4; ++i) {
            int row = 16*mt + 4*kg + i, col = 16*nt + r16;
            if (col < 4) {
                f32[DTLF + row*4 + col] = acc[i];
            } else if (col < 36) {
                int s = col - 4;
                unsigned uu = __float_as_uint(acc[i]);
                unsigned short hv = (unsigned short)((uu + 0x7fffu + ((uu>>16)&1u)) >> 16);  // RNE
                int idx = (s < 16) ? (8*(s>>2) + (s&3)) : (8*((s-16)>>2) + 4 + ((s-16)&3));
                u16[BCHU + row*32 + idx] = hv;
            }
        }
    }
    __syncthreads();

    // ---------- P4b + P5: dt precompute (regs) + selective scan
    {
        const int dd = tid >> 2;      // channel
        const int sq = tid & 3;       // quad lane: states [4sq,4sq+4), owns l with (l>>2)&3==sq
        f4 A4;
        A4.x = -__expf(Alog[dd*NS + 4*sq + 0]);
        A4.y = -__expf(Alog[dd*NS + 4*sq + 1]);
        A4.z = -__expf(Alog[dd*NS + 4*sq + 2]);
        A4.w = -__expf(Alog[dd*NS + 4*sq + 3]);
        const f4 wdt = *(const f4*)(Wdt + 4*dd);
        const float b0  = bdt[dd];
        const float Ddv = Dp[dd];
        float dtv[6][4];
        #pragma unroll
        for (int t = 0; t < 6; ++t)
            #pragma unroll
            for (int i = 0; i < 4; ++i) {
                int l = 16*t + 4*sq + i;
                f4 dl = *(const f4*)(f32 + DTLF + l*4);
                float dtr = dl.x*wdt.x + dl.y*wdt.y + dl.z*wdt.z + dl.w*wdt.w + b0;
                dtv[t][i] = (dtr > 20.f) ? dtr : __logf(1.f + __expf(dtr));
            }
        f4 h = {0.f,0.f,0.f,0.f};
        #pragma unroll
        for (int t = 0; t < 6; ++t) {
            #pragma unroll
            for (int j = 0; j < 16; ++j) {
                const int l = 16*t + j;
                const int so = j >> 2, i = j & 3;
                float dto = dtv[t][i];
                float dtb = (so==0) ? dppf<0x00>(dto) : (so==1) ? dppf<0x55>(dto)
                          : (so==2) ? dppf<0xAA>(dto) : dppf<0xFF>(dto);
                unsigned px = XCU[xcw(l, dd)];
                float xv = unpk(px);
                float uu = dtb * xv;
                u4v bcv = *(const u4v*)(u16 + BCHU + l*32 + 8*sq);
                float B0 = __uint_as_float(bcv.x << 16), B1 = __uint_as_float(bcv.x & 0xffff0000u);
                float B2 = __uint_as_float(bcv.y << 16), B3 = __uint_as_float(bcv.y & 0xffff0000u);
                float C0 = __uint_as_float(bcv.z << 16), C1 = __uint_as_float(bcv.z & 0xffff0000u);
                float C2 = __uint_as_float(bcv.w << 16), C3 = __uint_as_float(bcv.w & 0xffff0000u);
                h.x = __expf(dtb*A4.x)*h.x + uu*B0;
                h.y = __expf(dtb*A4.y)*h.y + uu*B1;
                h.z = __expf(dtb*A4.z)*h.z + uu*B2;
                h.w = __expf(dtb*A4.w)*h.w + uu*B3;
                float y = h.x*C0 + h.y*C1 + h.z*C2 + h.w*C3;
                y += dppf<0xB1>(y);           // quad xor1
                y += dppf<0x4E>(y);           // quad xor2
                if (sq == i) XCU[xcw(l, dd)] = packu(y + xv*Ddv);
            }
        }
    }
    // scan + P5b touch only this wave's channel range -> no barrier needed here

    // ---------- P5b: y *= silu(z) (zr in P2 D-layout; cols 16w..16w+16 = this wave's channels)
    #pragma unroll
    for (int mt = 0; mt < 6; ++mt) {
        #pragma unroll
        for (int i = 0; i < 4; ++i) {
            int row = 16*mt + 4*kg + i, col = 16*w + r16;
            unsigned p = XCU[xcw(row, col)];
            float y = unpk(p) * siluf(zr[mt][i]);
            XCU[xcw(row, col)] = packu(y);
        }
    }
    __syncthreads();

    // ---------- P8: h1 = safe(y @ Wout^T) -> h1T (bf16 hi/lo, transposed)
    for (int tt = w; tt < 24; tt += 8) {
        int mt = tt >> 2, nt = tt & 3;
        int nn = 16*nt + r16;
        f4 acc = {0.f,0.f,0.f,0.f};
        #pragma unroll
        for (int ks = 0; ks < 4; ++ks) {
            bf8 bh, bl; pack8(Wout + nn*DIN + 32*ks + 8*kg, bh, bl);
            bf8 ah, al; fragFromXC(XCU, 16*mt + r16, 8*kg + 32*ks, ah, al);
            acc = MFMA(ah, bh, acc); acc = MFMA(ah, bl, acc); acc = MFMA(al, bh, acc);
        }
        #pragma unroll
        for (int i = 0; i < 4; ++i) {
            int t = 16*mt + 4*kg + i, c = 16*nt + r16;
            unsigned short hh, ll; splitf(safef(acc[i]), hh, ll);
            int id = c*104 + t;
            u16[H1H + id] = hh; u16[H1L + id] = ll;
        }
    }
    __syncthreads();

    // ---------- P9: out[o][c] = safe( sum_t Wt[o][t]*h1[t][c] + bt[o] )
    for (int tt = w; tt < 24; tt += 8) {
        int mt = tt >> 2, nt = tt & 3;
        int oo = 16*mt + r16;
        f4 acc = {0.f,0.f,0.f,0.f};
        #pragma unroll
        for (int ks = 0; ks < 3; ++ks) {
            bf8 ah, al; pack8(Wt + oo*NT + 32*ks + 8*kg, ah, al);
            int c  = 16*nt + r16;
            int id = c*104 + 8*kg + 32*ks;
            bf8 bh = *(const bf8*)(u16 + H1H + id);
            bf8 bl = *(const bf8*)(u16 + H1L + id);
            acc = MFMA(ah, bh, acc); acc = MFMA(ah, bl, acc); acc = MFMA(al, bh, acc);
        }
        #pragma unroll
        for (int i = 0; i < 4; ++i) {
            int o = 16*mt + 4*kg + i, c = 16*nt + r16;
            out[((size_t)((n*NT + o)*NC + c))*NV + v] = safef(acc[i] + bt[o]);
        }
    }
}

extern "C" void kernel_launch(void* const* d_in, const int* in_sizes, int n_in,
                              void* d_out, int out_size, void* d_ws, size_t ws_size,
                              hipStream_t stream) {
    (void)hipFuncSetAttribute((const void*)mamba_mfma,
                              hipFuncAttributeMaxDynamicSharedMemorySize,
                              LDS_BYTES);
    mamba_mfma<<<dim3(NN*NV), dim3(NTH), LDS_BYTES, stream>>>(
        (const float*)d_in[0],  (const float*)d_in[1],  (const float*)d_in[2],
        (const float*)d_in[3],  (const float*)d_in[4],  (const float*)d_in[5],
        (const float*)d_in[6],  (const float*)d_in[7],  (const float*)d_in[8],
        (const float*)d_in[9],  (const float*)d_in[10], (const float*)d_in[11],
        (float*)d_out);
}